// Round 9
// baseline (20833.472 us; speedup 1.0000x reference)
//
#include <hip/hip_runtime.h>
#include <hip/hip_bf16.h>
#include <cstdint>
#include <cstddef>

#define T_STEPS 32768
#define DD 64
#define HH 128
#define GG 512   // 4*H

// d_out layout (float32, concatenated flat):
//   step (T,11) @0, experience (T,2) @360448, rsd (T,1) @425984, s (T,1) @458752
#define OFF_EXP 360448
#define OFF_RSD 425984
#define OFF_S   458752

typedef __attribute__((ext_vector_type(8))) _Float16 half8;
typedef __attribute__((ext_vector_type(4))) float f32x4;

__device__ __forceinline__ int   f2i(float x) { union { float f; int i; } u; u.f = x; return u.i; }
__device__ __forceinline__ float i2f(int x)   { union { int i; float f; } u; u.i = x; return u.f; }

__device__ __forceinline__ float exp2_f(float x) {
    float r; asm("v_exp_f32 %0, %1" : "=v"(r) : "v"(x)); return r;
}
__device__ __forceinline__ float sigm_fast(float x) {          // 1/(1+e^-x)
    return __builtin_amdgcn_rcpf(1.0f + exp2_f(x * -1.442695041f));
}
__device__ __forceinline__ float tanh_fast(float x) {          // 1 - 2/(1+e^2x)
    return __builtin_fmaf(
        __builtin_amdgcn_rcpf(1.0f + exp2_f(x * 2.885390082f)), -2.0f, 1.0f);
}
__device__ __forceinline__ unsigned packh2(float x, float y) {
    union { _Float16 h[2]; unsigned u; } c;
    c.h[0] = (_Float16)x; c.h[1] = (_Float16)y;
    return c.u;
}
// f16x2 dot with f32 accumulate, operands forced into arch VGPRs
#define D2(acc, wreg, hreg) \
    asm("v_dot2_f32_f16 %0, %1, %2, %0" : "+v"(acc) : "v"(wreg), "v"(hreg))

// ---------------------------------------------------------------------------
// Kernel 1: pregate, permuted per-cell: P[r][4*cell + g] = pregate of gate g
// of cell (thread j computes W row grow = (j&3)*128 + (j>>2)).
// ---------------------------------------------------------------------------
__global__ __launch_bounds__(512, 2) void pregate_kernel(
    const float* __restrict__ X, const float* __restrict__ W_ih,
    const float* __restrict__ b_ih, const float* __restrict__ b_hh,
    float* __restrict__ P, int t0, int nrows)
{
    __shared__ __align__(16) float xs[DD];
    const int j = threadIdx.x;
    const int grow = (j & 3) * HH + (j >> 2);

    float w[DD];
    const float4* wv = reinterpret_cast<const float4*>(W_ih + (size_t)grow * DD);
#pragma unroll
    for (int k = 0; k < DD / 4; ++k) {
        float4 v = wv[k];
        w[4*k+0] = v.x; w[4*k+1] = v.y; w[4*k+2] = v.z; w[4*k+3] = v.w;
    }
    const float bias = b_ih[grow] + b_hh[grow];

    const int rpb = (nrows + gridDim.x - 1) / gridDim.x;
    const int r0  = blockIdx.x * rpb;
    const int r1  = (r0 + rpb < nrows) ? (r0 + rpb) : nrows;

    for (int r = r0; r < r1; ++r) {
        const int t = t0 + r;
        if (j < DD) xs[j] = X[(size_t)t * DD + j];
        __syncthreads();
        float acc = bias;
        const float4* xv = reinterpret_cast<const float4*>(xs);
#pragma unroll
        for (int k = 0; k < DD / 4; ++k) {
            float4 v = xv[k];
            acc += v.x*w[4*k+0] + v.y*w[4*k+1] + v.z*w[4*k+2] + v.w*w[4*k+3];
        }
        P[(size_t)r * GG + j] = acc;
        __syncthreads();
    }
}

// ---------------------------------------------------------------------------
// Kernel 2: sequential LSTM, 1 block x 256 threads = 4 waves (1 per SIMD).
// DUAL-PIPE K-split:
//   K in [0,64):  MFMA — 8 independent 2-deep chains (2 col-blocks x 4 gates),
//                 16 MFMA/wave (A = h replicated, B = W_hh cols, AGPR-ok).
//   K in [64,128): VALU — per lane, own cell's 4 gates over a 32-wide slice
//                 (khalf = kgrp&1), 64 inline-asm v_dot2_f32_f16 (VGPR-pinned),
//                 partner slice summed via one ds_swizzle xor16 round.
// Lane (col,kgrp): blk=kgrp>>1 -> cell 32w+16blk+col; lane-local update;
// khalf0 publishes h (f16 LDS), khalf1 stores hist. ONE raw barrier/step.
// ---------------------------------------------------------------------------
__global__ __launch_bounds__(256, 1) void lstm_seq_kernel(
    const float* __restrict__ P, const float* __restrict__ W_hh,
    float* __restrict__ hist, float* __restrict__ state,
    int t0, int C)
{
    __shared__ __align__(16) _Float16 hh2[2][HH];

    const int j     = threadIdx.x;
    const int w     = j >> 6;        // wave 0..3
    const int l     = j & 63;
    const int col   = l & 15;
    const int kgrp  = l >> 4;        // 0..3
    const int blk   = kgrp >> 1;     // cell block within wave
    const int khalf = kgrp & 1;      // VALU K-slice selector
    const int mycell = 32 * w + 16 * blk + col;

    // MFMA B fragments (K 0..64): wf[s][mt][kt], kt in {0,1}
    half8 wf[2][4][2];
#pragma unroll
    for (int s = 0; s < 2; ++s) {
#pragma unroll
        for (int mt = 0; mt < 4; ++mt) {
            const float* wr =
                W_hh + (size_t)(mt * HH + 32 * w + 16 * s + col) * HH + 8 * kgrp;
#pragma unroll
            for (int kt = 0; kt < 2; ++kt) {
                const float* wp = wr + 32 * kt;
                float4 w0 = *reinterpret_cast<const float4*>(wp);
                float4 w1 = *reinterpret_cast<const float4*>(wp + 4);
                half8 hf;
                hf[0] = (_Float16)w0.x; hf[1] = (_Float16)w0.y;
                hf[2] = (_Float16)w0.z; hf[3] = (_Float16)w0.w;
                hf[4] = (_Float16)w1.x; hf[5] = (_Float16)w1.y;
                hf[6] = (_Float16)w1.z; hf[7] = (_Float16)w1.w;
                wf[s][mt][kt] = hf;
            }
        }
    }

    // VALU weights (K 64..128, own 32-slice): vw[g][k] packed f16x2
    unsigned vw[4][16];
#pragma unroll
    for (int g = 0; g < 4; ++g) {
        const float* wr = W_hh + (size_t)(g * HH + mycell) * HH + 64 + 32 * khalf;
#pragma unroll
        for (int k = 0; k < 16; ++k)
            vw[g][k] = packh2(wr[2*k], wr[2*k+1]);
    }

    float c = 0.0f;
    if (t0 != 0) c = state[HH + mycell];           // replicated across pair
    if (j < HH) hh2[0][j] = (_Float16)((t0 != 0) ? state[j] : 0.0f);
    __syncthreads();

    const float* Pme = P + 4 * (size_t)mycell;     // this cell's i,f,g,o
    const f32x4 Z = {0.0f, 0.0f, 0.0f, 0.0f};
    f32x4 pc  = *reinterpret_cast<const f32x4*>(Pme);
    f32x4 pn1 = (C > 1) ? *reinterpret_cast<const f32x4*>(Pme + GG) : Z;
    float hn = 0.0f;

#pragma unroll 1
    for (int r = 0; r < C; ++r) {
        const int cur = r & 1;
        // MFMA A fragments (K 0..64): 2 broadcast ds_read_b128
        const _Float16* hb = &hh2[cur][8 * kgrp];
        const half8 a0 = *reinterpret_cast<const half8*>(hb);
        const half8 a1 = *reinterpret_cast<const half8*>(hb + 32);
        // VALU h slice (32 f16 = 16 pairs): 4 broadcast b128 (2 addrs/wave)
        const uint4* hvp = reinterpret_cast<const uint4*>(&hh2[cur][64 + 32 * khalf]);
        const uint4 hv0 = hvp[0], hv1 = hvp[1], hv2 = hvp[2], hv3 = hvp[3];

        // P prefetch 2 steps ahead (in flight across the raw barrier)
        f32x4 pn2 = Z;
        if (r + 2 < C) pn2 = *reinterpret_cast<const f32x4*>(Pme + (size_t)(r + 2) * GG);

#define MF(A, B, Cc) __builtin_amdgcn_mfma_f32_16x16x32_f16((A), (B), (Cc), 0, 0, 0)
        // MFMA layer kt=0 (8 independent)
        f32x4 qa0 = MF(a0, wf[0][0][0], Z); f32x4 qa1 = MF(a0, wf[0][1][0], Z);
        f32x4 qa2 = MF(a0, wf[0][2][0], Z); f32x4 qa3 = MF(a0, wf[0][3][0], Z);
        f32x4 qb0 = MF(a0, wf[1][0][0], Z); f32x4 qb1 = MF(a0, wf[1][1][0], Z);
        f32x4 qb2 = MF(a0, wf[1][2][0], Z); f32x4 qb3 = MF(a0, wf[1][3][0], Z);

        // VALU dot2s fill the MFMA issue gaps (separate pipes)
        float d0 = 0.f, d1 = 0.f, d2 = 0.f, d3 = 0.f;
#define DP(hreg) { D2(d0, vw[0][kk], hreg); D2(d1, vw[1][kk], hreg); \
                   D2(d2, vw[2][kk], hreg); D2(d3, vw[3][kk], hreg); ++kk; }
        {
            int kk = 0;
            DP(hv0.x) DP(hv0.y) DP(hv0.z) DP(hv0.w)
            DP(hv1.x) DP(hv1.y) DP(hv1.z) DP(hv1.w)
            DP(hv2.x) DP(hv2.y) DP(hv2.z) DP(hv2.w)
            DP(hv3.x) DP(hv3.y) DP(hv3.z) DP(hv3.w)
        }
#undef DP
        // MFMA layer kt=1 (chained)
        qa0 = MF(a1, wf[0][0][1], qa0); qa1 = MF(a1, wf[0][1][1], qa1);
        qa2 = MF(a1, wf[0][2][1], qa2); qa3 = MF(a1, wf[0][3][1], qa3);
        qb0 = MF(a1, wf[1][0][1], qb0); qb1 = MF(a1, wf[1][1][1], qb1);
        qb2 = MF(a1, wf[1][2][1], qb2); qb3 = MF(a1, wf[1][3][1], qb3);
#undef MF

        // partner K-slice exchange (lane ^ 16), then merge
        d0 += i2f(__builtin_amdgcn_ds_swizzle(f2i(d0), 0x401F));
        d1 += i2f(__builtin_amdgcn_ds_swizzle(f2i(d1), 0x401F));
        d2 += i2f(__builtin_amdgcn_ds_swizzle(f2i(d2), 0x401F));
        d3 += i2f(__builtin_amdgcn_ds_swizzle(f2i(d3), 0x401F));

        const bool useB = (blk != 0);
        const float si = (useB ? qb0[0] : qa0[0]) + d0 + pc[0];
        const float sf = (useB ? qb1[0] : qa1[0]) + d1 + pc[1];
        const float sg = (useB ? qb2[0] : qa2[0]) + d2 + pc[2];
        const float so = (useB ? qb3[0] : qa3[0]) + d3 + pc[3];

        // lane-local LSTM cell update
        const float ai = sigm_fast(si);
        const float af = sigm_fast(sf);
        const float ag = tanh_fast(sg);
        const float ao = sigm_fast(so);
        c = __builtin_fmaf(af, c, ai * ag);
        hn = ao * tanh_fast(c);

        if (khalf == 0) hh2[cur ^ 1][mycell] = (_Float16)hn;
        else            hist[(size_t)r * HH + mycell] = hn;

        pc = pn1; pn1 = pn2;

        // one raw barrier: drain LDS only, global loads stay in flight
        asm volatile("s_waitcnt lgkmcnt(0)" ::: "memory");
        __builtin_amdgcn_s_barrier();
        __builtin_amdgcn_sched_barrier(0);
    }

    if (khalf == 0) {
        state[mycell]      = hn;
        state[HH + mycell] = c;
    }
}

// ---------------------------------------------------------------------------
// Kernel 3: heads, parallel over (t, output)
// ---------------------------------------------------------------------------
__global__ __launch_bounds__(256, 4) void heads_kernel(
    const float* __restrict__ hist,
    const float* __restrict__ W1, const float* __restrict__ b1,
    const float* __restrict__ W2, const float* __restrict__ b2,
    const float* __restrict__ W3, const float* __restrict__ b3,
    const float* __restrict__ W4, const float* __restrict__ b4,
    float* __restrict__ out, int t0, int C)
{
    const int idx = blockIdx.x * 256 + threadIdx.x;
    const int tr  = idx >> 4;
    const int oi  = idx & 15;
    if (tr >= C || oi >= 15) return;

    const float* wrow;
    float bias;
    if (oi < 11)       { wrow = W1 + oi * HH;        bias = b1[oi]; }
    else if (oi < 13)  { wrow = W2 + (oi - 11) * HH; bias = b2[oi - 11]; }
    else if (oi == 13) { wrow = W3;                  bias = b3[0]; }
    else               { wrow = W4;                  bias = b4[0]; }

    const float4* h4 = reinterpret_cast<const float4*>(hist + (size_t)tr * HH);
    const float4* w4 = reinterpret_cast<const float4*>(wrow);
    float s = bias;
#pragma unroll
    for (int k = 0; k < HH / 4; ++k) {
        float4 hv = h4[k];
        float4 wv = w4[k];
        s += hv.x*wv.x + hv.y*wv.y + hv.z*wv.z + hv.w*wv.w;
    }
    const int t = t0 + tr;
    if (oi < 11)       out[(size_t)t * 11 + oi] = s;
    else if (oi < 13)  out[OFF_EXP + (size_t)t * 2 + (oi - 11)] = s;
    else if (oi == 13) out[OFF_RSD + t] = s;
    else               out[OFF_S + t] = s;
}

// ---------------------------------------------------------------------------
extern "C" void kernel_launch(void* const* d_in, const int* in_sizes, int n_in,
                              void* d_out, int out_size, void* d_ws, size_t ws_size,
                              hipStream_t stream)
{
    const float* X    = (const float*)d_in[0];
    const float* W_ih = (const float*)d_in[1];
    const float* W_hh = (const float*)d_in[2];
    const float* b_ih = (const float*)d_in[3];
    const float* b_hh = (const float*)d_in[4];
    const float* W1   = (const float*)d_in[5];
    const float* b1   = (const float*)d_in[6];
    const float* W2   = (const float*)d_in[7];
    const float* b2   = (const float*)d_in[8];
    const float* W3   = (const float*)d_in[9];
    const float* b3   = (const float*)d_in[10];
    const float* W4   = (const float*)d_in[11];
    const float* b4   = (const float*)d_in[12];

    float* out   = (float*)d_out;
    float* state = (float*)d_ws;   // 256 floats: h then c

    // ws: state(1KB) | hist(C*128 f32) | P(C*512 f32)  => 2560 B/row
    size_t avail = (ws_size > 1024) ? (ws_size - 1024) / 2560 : 0;
    int C = (avail >= (size_t)T_STEPS) ? T_STEPS : (int)avail;
    if (C < 1) C = 1;
    float* hist = state + 256;
    float* P    = hist + (size_t)C * HH;

    for (int t0 = 0; t0 < T_STEPS; t0 += C) {
        const int Cc = (C < T_STEPS - t0) ? C : (T_STEPS - t0);
        const int nb = (Cc < 512) ? Cc : 512;
        pregate_kernel<<<nb, 512, 0, stream>>>(X, W_ih, b_ih, b_hh, P, t0, Cc);
        lstm_seq_kernel<<<1, 256, 0, stream>>>(P, W_hh, hist, state, t0, Cc);
        heads_kernel<<<(Cc * 16 + 255) / 256, 256, 0, stream>>>(
            hist, W1, b1, W2, b2, W3, b3, W4, b4, out, t0, Cc);
    }
}